// Round 5
// baseline (404.741 us; speedup 1.0000x reference)
//
#include <hip/hip_runtime.h>
#include <hip/hip_bf16.h>

typedef __bf16 bf16_8  __attribute__((ext_vector_type(8)));
typedef __bf16 bf16_4  __attribute__((ext_vector_type(4)));
typedef __bf16 bf16_16 __attribute__((ext_vector_type(16)));
typedef float  f32_4   __attribute__((ext_vector_type(4)));
typedef float  f32_16  __attribute__((ext_vector_type(16)));

#define NH 16
#define DHD 64
#define BB 2
#define SS 2048
#define DD 1024

// async global->LDS, 16B per lane; LDS dest must be wave-uniform base + lane*16
__device__ __forceinline__ void gload16(const __bf16* g, __bf16* l) {
    __builtin_amdgcn_global_load_lds(
        (const __attribute__((address_space(1))) void*)g,
        (__attribute__((address_space(3))) void*)l, 16, 0, 0);
}

// ---------------------------------------------------------------------------
// f32 -> bf16 conversions, one kernel (y selects tensor)
// ---------------------------------------------------------------------------
__global__ __launch_bounds__(256) void conv_all(
    const float* __restrict__ s0, const float* __restrict__ s1,
    const float* __restrict__ s2, const float* __restrict__ s3,
    const float* __restrict__ s4, const float* __restrict__ s5,
    __bf16* __restrict__ d0, __bf16* __restrict__ d1, __bf16* __restrict__ d2,
    __bf16* __restrict__ d3, __bf16* __restrict__ d4, __bf16* __restrict__ d5) {
    const int y = blockIdx.y;
    if (y >= 2 && blockIdx.x >= 1024) return;
    const float* s = (y == 0) ? s0 : (y == 1) ? s1 : (y == 2) ? s2
                   : (y == 3) ? s3 : (y == 4) ? s4 : s5;
    __bf16* d      = (y == 0) ? d0 : (y == 1) ? d1 : (y == 2) ? d2
                   : (y == 3) ? d3 : (y == 4) ? d4 : d5;
    const int i = (blockIdx.x * 256 + threadIdx.x) * 4;
    f32_4 v = *(const f32_4*)&s[i];
    bf16_4 o; o[0] = (__bf16)v[0]; o[1] = (__bf16)v[1];
    o[2] = (__bf16)v[2]; o[3] = (__bf16)v[3];
    *(bf16_4*)&d[i] = o;
}

// ---------------------------------------------------------------------------
// mask summary: flag[b][qt64][kt64] = 1 if any zero in that 64x64 tile
// ---------------------------------------------------------------------------
__global__ __launch_bounds__(256) void mask_flags_k(const int* __restrict__ mask,
                                                    int* __restrict__ flags) {
    const int id = blockIdx.x;  // b*1024 + qt*32 + kt
    const int b = id >> 10, qt = (id >> 5) & 31, kt = id & 31;
    const int t = threadIdx.x;
    const int row = t >> 2, seg = t & 3;
    const int* p = mask + ((size_t)b * SS + qt * 64 + row) * SS + kt * 64 + seg * 16;
    int any0 = 0;
#pragma unroll
    for (int i = 0; i < 4; ++i) {
        int4 v = *(const int4*)&p[i * 4];
        any0 |= (v.x == 0) | (v.y == 0) | (v.z == 0) | (v.w == 0);
    }
    unsigned long long bal = __ballot(any0);
    __shared__ int sf[4];
    if ((t & 63) == 0) sf[t >> 6] = (bal != 0ULL);
    __syncthreads();
    if (t == 0) flags[id] = sf[0] | sf[1] | sf[2] | sf[3];
}

// ---------------------------------------------------------------------------
// 128x128 GEMM (m97 recipe), C = A * W^T + bias
// LAYOUT 0: (b,h,s,dh) bf16;  LAYOUT 2: V^T (b,h,dh,s) bf16 packed stores.
// ---------------------------------------------------------------------------
template <int LAYOUT>
__device__ __forceinline__ void gemm_body(const __bf16* __restrict__ A,
                                          const __bf16* __restrict__ W,
                                          const float* __restrict__ bias,
                                          __bf16* __restrict__ out,
                                          __bf16* ldsA, __bf16* ldsB) {
    const int tid  = threadIdx.x;
    const int lane = tid & 63;
    const int w    = tid >> 6;
    const int quad = lane >> 4;
    const int l15  = lane & 15;
    const int wm   = (w >> 1) * 64;
    const int wn   = (w & 1) * 64;
    const int m0   = blockIdx.x * 128;
    const int n0   = blockIdx.y * 128;

    f32_4 acc[4][4] = {};

    for (int kt = 0; kt < 1024; kt += 32) {
#pragma unroll
        for (int cc = 0; cc < 2; ++cc) {
            const int c   = tid + cc * 256;
            const int row = c >> 2;
            const int cp  = c & 3;
            gload16(&A[(size_t)(m0 + row) * 1024 + kt + cp * 8], &ldsA[c * 8]);
            gload16(&W[(size_t)(n0 + row) * 1024 + kt + cp * 8], &ldsB[c * 8]);
        }
        __syncthreads();

        bf16_8 af[4], bfr[4];
#pragma unroll
        for (int i = 0; i < 4; ++i)
            af[i] = *(const bf16_8*)&ldsA[(wm + i * 16 + l15) * 32 + quad * 8];
#pragma unroll
        for (int j = 0; j < 4; ++j)
            bfr[j] = *(const bf16_8*)&ldsB[(wn + j * 16 + l15) * 32 + quad * 8];
#pragma unroll
        for (int i = 0; i < 4; ++i)
#pragma unroll
            for (int j = 0; j < 4; ++j)
                acc[i][j] = __builtin_amdgcn_mfma_f32_16x16x32_bf16(
                    af[i], bfr[j], acc[i][j], 0, 0, 0);
        __syncthreads();
    }

#pragma unroll
    for (int i = 0; i < 4; ++i) {
#pragma unroll
        for (int j = 0; j < 4; ++j) {
            const int col = n0 + wn + j * 16 + l15;
            const float bv = bias[col];
            if (LAYOUT == 2) {
                const int row0 = m0 + wm + i * 16 + quad * 4;
                bf16_4 pk;
#pragma unroll
                for (int r = 0; r < 4; ++r) pk[r] = (__bf16)(acc[i][j][r] + bv);
                const int bb = row0 >> 11, s0 = row0 & 2047;
                const int h = col >> 6, dh = col & 63;
                *(bf16_4*)&out[(((size_t)bb * NH + h) * DHD + dh) * SS + s0] = pk;
            } else {
#pragma unroll
                for (int r = 0; r < 4; ++r) {
                    const int row = m0 + wm + i * 16 + quad * 4 + r;
                    out[(((size_t)(row >> 11) * NH + (col >> 6)) * SS +
                         (row & 2047)) * DHD + (col & 63)] =
                        (__bf16)(acc[i][j][r] + bv);
                }
            }
        }
    }
}

__global__ __launch_bounds__(256) void gemm_qkv(
    const __bf16* __restrict__ Xq, const __bf16* __restrict__ Xkv,
    const __bf16* __restrict__ Wq, const float* __restrict__ bq,
    const __bf16* __restrict__ Wk, const float* __restrict__ bk,
    const __bf16* __restrict__ Wv, const float* __restrict__ bv,
    __bf16* __restrict__ Qo, __bf16* __restrict__ Ko, __bf16* __restrict__ VTo) {
    __shared__ __align__(16) __bf16 ldsA[128 * 32];
    __shared__ __align__(16) __bf16 ldsB[128 * 32];
    const int z = blockIdx.z;
    const __bf16* A    = (z == 0) ? Xq : Xkv;
    const __bf16* W    = (z == 0) ? Wq : (z == 1 ? Wk : Wv);
    const float* bias  = (z == 0) ? bq : (z == 1 ? bk : bv);
    if (z == 2)
        gemm_body<2>(A, W, bias, VTo, ldsA, ldsB);
    else
        gemm_body<0>(A, W, bias, (z == 0) ? Qo : Ko, ldsA, ldsB);
}

// ---------------------------------------------------------------------------
// Final projection: 64x64 tile, BK=32, 1024 blocks (4/CU). out = f32 row-major.
// ---------------------------------------------------------------------------
__global__ __launch_bounds__(256) void gemm_final(
    const __bf16* __restrict__ A, const __bf16* __restrict__ W,
    const float* __restrict__ bias, float* __restrict__ out) {
    __shared__ __align__(16) __bf16 ldsA[64 * 32];
    __shared__ __align__(16) __bf16 ldsB[64 * 32];
    const int tid  = threadIdx.x;
    const int lane = tid & 63;
    const int w    = tid >> 6;
    const int quad = lane >> 4;
    const int l15  = lane & 15;
    const int wm   = (w >> 1) * 32;
    const int wn   = (w & 1) * 32;
    const int m0   = blockIdx.x * 64;
    const int n0   = blockIdx.y * 64;

    const int isB = w >> 1;
    const __bf16* src = isB ? W : A;
    const int     bN  = isB ? n0 : m0;
    __bf16*       dst = isB ? ldsB : ldsA;
    const int     w2  = w & 1;

    f32_4 acc[2][2] = {};

    for (int kt = 0; kt < 1024; kt += 32) {
#pragma unroll
        for (int cc = 0; cc < 2; ++cc) {
            const int c   = w2 * 128 + cc * 64 + lane;
            const int row = c >> 2;
            const int cp  = c & 3;
            gload16(&src[(size_t)(bN + row) * 1024 + kt + cp * 8], &dst[c * 8]);
        }
        __syncthreads();

        bf16_8 af[2], bfr[2];
#pragma unroll
        for (int i = 0; i < 2; ++i)
            af[i] = *(const bf16_8*)&ldsA[(wm + i * 16 + l15) * 32 + quad * 8];
#pragma unroll
        for (int j = 0; j < 2; ++j)
            bfr[j] = *(const bf16_8*)&ldsB[(wn + j * 16 + l15) * 32 + quad * 8];
#pragma unroll
        for (int i = 0; i < 2; ++i)
#pragma unroll
            for (int j = 0; j < 2; ++j)
                acc[i][j] = __builtin_amdgcn_mfma_f32_16x16x32_bf16(
                    af[i], bfr[j], acc[i][j], 0, 0, 0);
        __syncthreads();
    }

#pragma unroll
    for (int i = 0; i < 2; ++i)
#pragma unroll
        for (int j = 0; j < 2; ++j) {
            const int col = n0 + wn + j * 16 + l15;
            const float bv = bias[col];
#pragma unroll
            for (int r = 0; r < 4; ++r) {
                const int row = m0 + wm + i * 16 + quad * 4 + r;
                out[(size_t)row * 1024 + col] = acc[i][j][r] + bv;
            }
        }
}

// ---------------------------------------------------------------------------
// Flash attention v2: 32x32x16 MFMA (2x FLOP per LDS byte vs 16x16x32).
// Block = 128 threads (2 waves), q-tile 64 (32 q-rows/wave), k-tiles of 64.
// LDS: ldsKP (K tile, reused for P after barrier2) + ldsVT. 18.4 KB total.
// A/B-frag 32x32x16: m/n = lane&31, k = (lane>>5)*8 + j (slice of 16).
// C/D: col = lane&31, row = (reg&3) + 8*(reg>>2) + 4*(lane>>5)  [m74/m101].
// No-max softmax in exp2 domain (Q pre-scaled by 0.125*log2e).
// ---------------------------------------------------------------------------
__global__ __launch_bounds__(128, 3) void flash_attn(
    const __bf16* __restrict__ Q, const __bf16* __restrict__ K,
    const __bf16* __restrict__ VT, const int* __restrict__ mask,
    const int* __restrict__ flags, __bf16* __restrict__ O) {
    __shared__ __align__(16) __bf16 ldsKP[64 * 72];
    __shared__ __align__(16) __bf16 ldsVT[64 * 72];

    const int tid  = threadIdx.x;
    const int lane = tid & 63;
    const int w    = tid >> 6;   // 0..1
    const int l31  = lane & 31;
    const int hl   = lane >> 5;  // 0..1
    const int q0   = blockIdx.x * 64;
    const int bh   = blockIdx.y;
    const int b    = bh >> 4;

    const __bf16* Qb  = Q + (size_t)bh * SS * DHD;
    const __bf16* Kb  = K + (size_t)bh * SS * DHD;
    const __bf16* VTb = VT + (size_t)bh * DHD * SS;
    const int*    mb  = mask + (size_t)b * SS * SS;
    const int*    fl  = flags + ((size_t)b * 32 + blockIdx.x) * 32;

    // Q A-frags: Q[q0+w*32+l31][ks*16 + hl*8 + j], pre-scaled 0.125*log2(e)
    bf16_8 qa[4];
#pragma unroll
    for (int ks = 0; ks < 4; ++ks) {
        bf16_8 t = *(const bf16_8*)&Qb[(size_t)(q0 + w * 32 + l31) * DHD +
                                       ks * 16 + hl * 8];
#pragma unroll
        for (int e = 0; e < 8; ++e)
            qa[ks][e] = (__bf16)((float)t[e] * 0.18033688011112042f);
    }

    f32_16 of0 = {}, of1 = {};
    float li[16];
#pragma unroll
    for (int r = 0; r < 16; ++r) li[r] = 0.f;

    // staging: 1024 x 16B chunks over 128 lanes -> 8 per lane (4 K, 4 VT)
    const int rK = tid >> 3;   // 0..15
    const int cp = tid & 7;
    uint4 pre[8];
#pragma unroll
    for (int i = 0; i < 4; ++i) {
        pre[i]     = *(const uint4*)&Kb[(size_t)(rK + i * 16) * DHD + cp * 8];
        pre[4 + i] = *(const uint4*)&VTb[(size_t)(rK + i * 16) * SS + cp * 8];
    }

    for (int k0 = 0; k0 < SS; k0 += 64) {
#pragma unroll
        for (int i = 0; i < 4; ++i) {
            *(uint4*)&ldsKP[(rK + i * 16) * 72 + cp * 8] = pre[i];
            *(uint4*)&ldsVT[(rK + i * 16) * 72 + cp * 8] = pre[4 + i];
        }
        if (k0 + 64 < SS) {
            const int kn = k0 + 64;
#pragma unroll
            for (int i = 0; i < 4; ++i) {
                pre[i]     = *(const uint4*)&Kb[(size_t)(kn + rK + i * 16) * DHD + cp * 8];
                pre[4 + i] = *(const uint4*)&VTb[(size_t)(rK + i * 16) * SS + kn + cp * 8];
            }
        }
        __syncthreads();  // staged tile visible

        const bool msk = (fl[k0 >> 6] != 0);
        bf16_16 p16[2];

        // S = (Q') K^T : per jtile 32 keys, K-dim = dh 64 = 4 slices of 16
#pragma unroll
        for (int jt = 0; jt < 2; ++jt) {
            f32_16 s = {};
#pragma unroll
            for (int ks = 0; ks < 4; ++ks) {
                bf16_8 kb = *(const bf16_8*)&ldsKP[(jt * 32 + l31) * 72 +
                                                   ks * 16 + hl * 8];
                s = __builtin_amdgcn_mfma_f32_32x32x16_bf16(qa[ks], kb, s, 0, 0, 0);
            }
            if (msk) {
#pragma unroll
                for (int r = 0; r < 16; ++r) {
                    const int row = (r & 3) + 8 * (r >> 2) + 4 * hl;
                    const int qg  = q0 + w * 32 + row;
                    const int kg  = k0 + jt * 32 + l31;
                    if (mb[(size_t)qg * SS + kg] == 0) s[r] = -1e9f;
                }
            }
#pragma unroll
            for (int r = 0; r < 16; ++r) {
                const float p = exp2f(s[r]);
                li[r] += p;
                p16[jt][r] = (__bf16)p;
            }
        }
        __syncthreads();  // all kb reads done; safe to overwrite K with P

        // P scatter: ldsKP[q-local][key-local]
#pragma unroll
        for (int jt = 0; jt < 2; ++jt)
#pragma unroll
            for (int r = 0; r < 16; ++r) {
                const int row = (r & 3) + 8 * (r >> 2) + 4 * hl;
                ldsKP[(w * 32 + row) * 72 + jt * 32 + l31] = p16[jt][r];
            }

        // O += P V  (A = P from ldsKP, B = V from ldsVT; same-wave lgkmcnt
        // orders this wave's P writes before its reads; cross-wave P rows are
        // private per wave (w*32 span), so no barrier needed here)
#pragma unroll
        for (int ks2 = 0; ks2 < 4; ++ks2) {
            bf16_8 pa = *(const bf16_8*)&ldsKP[(w * 32 + l31) * 72 +
                                               ks2 * 16 + hl * 8];
            bf16_8 vb0 = *(const bf16_8*)&ldsVT[(l31) * 72 + ks2 * 16 + hl * 8];
            bf16_8 vb1 = *(const bf16_8*)&ldsVT[(32 + l31) * 72 + ks2 * 16 + hl * 8];
            of0 = __builtin_amdgcn_mfma_f32_32x32x16_bf16(pa, vb0, of0, 0, 0, 0);
            of1 = __builtin_amdgcn_mfma_f32_32x32x16_bf16(pa, vb1, of1, 0, 0, 0);
        }
        __syncthreads();  // PV reads done before next staging overwrites
    }

    // reduce li across the 32 key-lanes (xor within l31), normalize, store O
    const int hcol = (bh & 15) * 64;
#pragma unroll
    for (int r = 0; r < 16; ++r) {
        float ls = li[r];
        ls += __shfl_xor(ls, 1);
        ls += __shfl_xor(ls, 2);
        ls += __shfl_xor(ls, 4);
        ls += __shfl_xor(ls, 8);
        ls += __shfl_xor(ls, 16);
        const float inv = 1.0f / fmaxf(ls, 1e-37f);
        const int row = (r & 3) + 8 * (r >> 2) + 4 * hl;
        const int qg  = q0 + w * 32 + row;
        O[((size_t)b * SS + qg) * DD + hcol + l31]      = (__bf16)(of0[r] * inv);
        O[((size_t)b * SS + qg) * DD + hcol + 32 + l31] = (__bf16)(of1[r] * inv);
    }
}

// ---------------------------------------------------------------------------

extern "C" void kernel_launch(void* const* d_in, const int* in_sizes, int n_in,
                              void* d_out, int out_size, void* d_ws, size_t ws_size,
                              hipStream_t stream) {
    const float* xq   = (const float*)d_in[0];
    const float* xkv  = (const float*)d_in[1];
    const int*   mask = (const int*)d_in[2];
    const float* Wq   = (const float*)d_in[3];
    const float* bq   = (const float*)d_in[4];
    const float* Wk   = (const float*)d_in[5];
    const float* bk   = (const float*)d_in[6];
    const float* Wv   = (const float*)d_in[7];
    const float* bv   = (const float*)d_in[8];
    const float* Wo   = (const float*)d_in[9];
    const float* bo   = (const float*)d_in[10];

    __bf16* ws = (__bf16*)d_ws;
    const size_t big = (size_t)BB * SS * DD;  // 4,194,304
    const size_t wsz = (size_t)DD * DD;       // 1,048,576
    __bf16* Qw   = ws;
    __bf16* Kw   = Qw + big;
    __bf16* VTw  = Kw + big;
    __bf16* Aw   = VTw + big;
    __bf16* Xqb  = Aw + big;
    __bf16* Xkvb = Xqb + big;
    __bf16* Wqb  = Xkvb + big;
    __bf16* Wkb  = Wqb + wsz;
    __bf16* Wvb  = Wkb + wsz;
    __bf16* Wob  = Wvb + wsz;
    int* flags   = (int*)(Wob + wsz);  // 2048 ints

    conv_all<<<dim3(4096, 6), dim3(256), 0, stream>>>(xq, xkv, Wq, Wk, Wv, Wo,
                                                      Xqb, Xkvb, Wqb, Wkb, Wvb, Wob);
    mask_flags_k<<<dim3(2048), dim3(256), 0, stream>>>(mask, flags);
    gemm_qkv<<<dim3(32, 8, 3), dim3(256), 0, stream>>>(Xqb, Xkvb, Wqb, bq, Wkb, bk,
                                                       Wvb, bv, Qw, Kw, VTw);
    flash_attn<<<dim3(SS / 64, BB * NH), dim3(128), 0, stream>>>(Qw, Kw, VTw, mask,
                                                                 flags, Aw);
    gemm_final<<<dim3(64, 16), dim3(256), 0, stream>>>(Aw, Wob, bo, (float*)d_out);
}

// Round 7
// 358.061 us; speedup vs baseline: 1.1304x; 1.1304x over previous
//
#include <hip/hip_runtime.h>
#include <hip/hip_bf16.h>

typedef __bf16 bf16_8  __attribute__((ext_vector_type(8)));
typedef __bf16 bf16_4  __attribute__((ext_vector_type(4)));
typedef float  f32_4   __attribute__((ext_vector_type(4)));
typedef float  f32_16  __attribute__((ext_vector_type(16)));

#define NH 16
#define DHD 64
#define BB 2
#define SS 2048
#define DD 1024

// async global->LDS, 16B per lane; LDS dest must be wave-uniform base + lane*16
__device__ __forceinline__ void gload16(const __bf16* g, __bf16* l) {
    __builtin_amdgcn_global_load_lds(
        (const __attribute__((address_space(1))) void*)g,
        (__attribute__((address_space(3))) void*)l, 16, 0, 0);
}

// ---------------------------------------------------------------------------
// f32 -> bf16 conversions, one kernel (y selects tensor)
// ---------------------------------------------------------------------------
__global__ __launch_bounds__(256) void conv_all(
    const float* __restrict__ s0, const float* __restrict__ s1,
    const float* __restrict__ s2, const float* __restrict__ s3,
    const float* __restrict__ s4, const float* __restrict__ s5,
    __bf16* __restrict__ d0, __bf16* __restrict__ d1, __bf16* __restrict__ d2,
    __bf16* __restrict__ d3, __bf16* __restrict__ d4, __bf16* __restrict__ d5) {
    const int y = blockIdx.y;
    if (y >= 2 && blockIdx.x >= 1024) return;
    const float* s = (y == 0) ? s0 : (y == 1) ? s1 : (y == 2) ? s2
                   : (y == 3) ? s3 : (y == 4) ? s4 : s5;
    __bf16* d      = (y == 0) ? d0 : (y == 1) ? d1 : (y == 2) ? d2
                   : (y == 3) ? d3 : (y == 4) ? d4 : d5;
    const int i = (blockIdx.x * 256 + threadIdx.x) * 4;
    f32_4 v = *(const f32_4*)&s[i];
    bf16_4 o; o[0] = (__bf16)v[0]; o[1] = (__bf16)v[1];
    o[2] = (__bf16)v[2]; o[3] = (__bf16)v[3];
    *(bf16_4*)&d[i] = o;
}

// ---------------------------------------------------------------------------
// mask summary: flag[b][qt64][kt64] = 1 if any zero in that 64x64 tile
// ---------------------------------------------------------------------------
__global__ __launch_bounds__(256) void mask_flags_k(const int* __restrict__ mask,
                                                    int* __restrict__ flags) {
    const int id = blockIdx.x;  // b*1024 + qt*32 + kt
    const int b = id >> 10, qt = (id >> 5) & 31, kt = id & 31;
    const int t = threadIdx.x;
    const int row = t >> 2, seg = t & 3;
    const int* p = mask + ((size_t)b * SS + qt * 64 + row) * SS + kt * 64 + seg * 16;
    int any0 = 0;
#pragma unroll
    for (int i = 0; i < 4; ++i) {
        int4 v = *(const int4*)&p[i * 4];
        any0 |= (v.x == 0) | (v.y == 0) | (v.z == 0) | (v.w == 0);
    }
    unsigned long long bal = __ballot(any0);
    __shared__ int sf[4];
    if ((t & 63) == 0) sf[t >> 6] = (bal != 0ULL);
    __syncthreads();
    if (t == 0) flags[id] = sf[0] | sf[1] | sf[2] | sf[3];
}

// ---------------------------------------------------------------------------
// 128x128 GEMM (m97 recipe), C = A * W^T + bias
// LAYOUT 0: (b,h,s,dh) bf16;  LAYOUT 2: V^T (b,h,dh,s) bf16 packed stores.
// ---------------------------------------------------------------------------
template <int LAYOUT>
__device__ __forceinline__ void gemm_body(const __bf16* __restrict__ A,
                                          const __bf16* __restrict__ W,
                                          const float* __restrict__ bias,
                                          __bf16* __restrict__ out,
                                          __bf16* ldsA, __bf16* ldsB) {
    const int tid  = threadIdx.x;
    const int lane = tid & 63;
    const int w    = tid >> 6;
    const int quad = lane >> 4;
    const int l15  = lane & 15;
    const int wm   = (w >> 1) * 64;
    const int wn   = (w & 1) * 64;
    const int m0   = blockIdx.x * 128;
    const int n0   = blockIdx.y * 128;

    f32_4 acc[4][4] = {};

    for (int kt = 0; kt < 1024; kt += 32) {
#pragma unroll
        for (int cc = 0; cc < 2; ++cc) {
            const int c   = tid + cc * 256;
            const int row = c >> 2;
            const int cp  = c & 3;
            gload16(&A[(size_t)(m0 + row) * 1024 + kt + cp * 8], &ldsA[c * 8]);
            gload16(&W[(size_t)(n0 + row) * 1024 + kt + cp * 8], &ldsB[c * 8]);
        }
        __syncthreads();

        bf16_8 af[4], bfr[4];
#pragma unroll
        for (int i = 0; i < 4; ++i)
            af[i] = *(const bf16_8*)&ldsA[(wm + i * 16 + l15) * 32 + quad * 8];
#pragma unroll
        for (int j = 0; j < 4; ++j)
            bfr[j] = *(const bf16_8*)&ldsB[(wn + j * 16 + l15) * 32 + quad * 8];
#pragma unroll
        for (int i = 0; i < 4; ++i)
#pragma unroll
            for (int j = 0; j < 4; ++j)
                acc[i][j] = __builtin_amdgcn_mfma_f32_16x16x32_bf16(
                    af[i], bfr[j], acc[i][j], 0, 0, 0);
        __syncthreads();
    }

#pragma unroll
    for (int i = 0; i < 4; ++i) {
#pragma unroll
        for (int j = 0; j < 4; ++j) {
            const int col = n0 + wn + j * 16 + l15;
            const float bv = bias[col];
            if (LAYOUT == 2) {
                const int row0 = m0 + wm + i * 16 + quad * 4;
                bf16_4 pk;
#pragma unroll
                for (int r = 0; r < 4; ++r) pk[r] = (__bf16)(acc[i][j][r] + bv);
                const int bb = row0 >> 11, s0 = row0 & 2047;
                const int h = col >> 6, dh = col & 63;
                *(bf16_4*)&out[(((size_t)bb * NH + h) * DHD + dh) * SS + s0] = pk;
            } else {
#pragma unroll
                for (int r = 0; r < 4; ++r) {
                    const int row = m0 + wm + i * 16 + quad * 4 + r;
                    out[(((size_t)(row >> 11) * NH + (col >> 6)) * SS +
                         (row & 2047)) * DHD + (col & 63)] =
                        (__bf16)(acc[i][j][r] + bv);
                }
            }
        }
    }
}

__global__ __launch_bounds__(256) void gemm_qkv(
    const __bf16* __restrict__ Xq, const __bf16* __restrict__ Xkv,
    const __bf16* __restrict__ Wq, const float* __restrict__ bq,
    const __bf16* __restrict__ Wk, const float* __restrict__ bk,
    const __bf16* __restrict__ Wv, const float* __restrict__ bv,
    __bf16* __restrict__ Qo, __bf16* __restrict__ Ko, __bf16* __restrict__ VTo) {
    __shared__ __align__(16) __bf16 ldsA[128 * 32];
    __shared__ __align__(16) __bf16 ldsB[128 * 32];
    const int z = blockIdx.z;
    const __bf16* A    = (z == 0) ? Xq : Xkv;
    const __bf16* W    = (z == 0) ? Wq : (z == 1 ? Wk : Wv);
    const float* bias  = (z == 0) ? bq : (z == 1 ? bk : bv);
    if (z == 2)
        gemm_body<2>(A, W, bias, VTo, ldsA, ldsB);
    else
        gemm_body<0>(A, W, bias, (z == 0) ? Qo : Ko, ldsA, ldsB);
}

// ---------------------------------------------------------------------------
// Final projection: 64x64 tile, BK=32, 1024 blocks (4/CU). out = f32 row-major.
// ---------------------------------------------------------------------------
__global__ __launch_bounds__(256) void gemm_final(
    const __bf16* __restrict__ A, const __bf16* __restrict__ W,
    const float* __restrict__ bias, float* __restrict__ out) {
    __shared__ __align__(16) __bf16 ldsA[64 * 32];
    __shared__ __align__(16) __bf16 ldsB[64 * 32];
    const int tid  = threadIdx.x;
    const int lane = tid & 63;
    const int w    = tid >> 6;
    const int quad = lane >> 4;
    const int l15  = lane & 15;
    const int wm   = (w >> 1) * 32;
    const int wn   = (w & 1) * 32;
    const int m0   = blockIdx.x * 64;
    const int n0   = blockIdx.y * 64;

    const int isB = w >> 1;
    const __bf16* src = isB ? W : A;
    const int     bN  = isB ? n0 : m0;
    __bf16*       dst = isB ? ldsB : ldsA;
    const int     w2  = w & 1;

    f32_4 acc[2][2] = {};

    for (int kt = 0; kt < 1024; kt += 32) {
#pragma unroll
        for (int cc = 0; cc < 2; ++cc) {
            const int c   = w2 * 128 + cc * 64 + lane;
            const int row = c >> 2;
            const int cp  = c & 3;
            gload16(&src[(size_t)(bN + row) * 1024 + kt + cp * 8], &dst[c * 8]);
        }
        __syncthreads();

        bf16_8 af[2], bfr[2];
#pragma unroll
        for (int i = 0; i < 2; ++i)
            af[i] = *(const bf16_8*)&ldsA[(wm + i * 16 + l15) * 32 + quad * 8];
#pragma unroll
        for (int j = 0; j < 2; ++j)
            bfr[j] = *(const bf16_8*)&ldsB[(wn + j * 16 + l15) * 32 + quad * 8];
#pragma unroll
        for (int i = 0; i < 2; ++i)
#pragma unroll
            for (int j = 0; j < 2; ++j)
                acc[i][j] = __builtin_amdgcn_mfma_f32_16x16x32_bf16(
                    af[i], bfr[j], acc[i][j], 0, 0, 0);
        __syncthreads();
    }

#pragma unroll
    for (int i = 0; i < 2; ++i)
#pragma unroll
        for (int j = 0; j < 2; ++j) {
            const int col = n0 + wn + j * 16 + l15;
            const float bv = bias[col];
#pragma unroll
            for (int r = 0; r < 4; ++r) {
                const int row = m0 + wm + i * 16 + quad * 4 + r;
                out[(size_t)row * 1024 + col] = acc[i][j][r] + bv;
            }
        }
}

// ---------------------------------------------------------------------------
// Flash attention v4: 32x32x16 MFMA, spill-free, round-5 barrier skeleton.
// Block = 128 threads (2 waves), q-tile 64 (32 q-rows/wave), k-tiles of 64.
// 3 barriers/tile: A (staging visible), M (P scatter visible / K reads done),
// B (VT/P reads done before next staging). No same-wave LDS-ordering
// assumptions (round 6 removed barrier M and diverged under graph replay).
// launch_bounds(128,2) -> VGPR cap 256: live ~130, no scratch spill.
// A/B-frag 32x32x16: m/n = lane&31, k = (lane>>5)*8 + j.
// C/D: col = lane&31, row = (reg&3) + 8*(reg>>2) + 4*(lane>>5)  [m74/m101].
// No-max softmax in exp2 domain (Q pre-scaled by 0.125*log2e).
// ---------------------------------------------------------------------------
__global__ __launch_bounds__(128, 2) void flash_attn(
    const __bf16* __restrict__ Q, const __bf16* __restrict__ K,
    const __bf16* __restrict__ VT, const int* __restrict__ mask,
    const int* __restrict__ flags, __bf16* __restrict__ O) {
    __shared__ __align__(16) __bf16 ldsK[64 * 72];
    __shared__ __align__(16) __bf16 ldsVT[64 * 72];
    __shared__ __align__(16) __bf16 ldsP[64 * 72];

    const int tid  = threadIdx.x;
    const int lane = tid & 63;
    const int w    = tid >> 6;   // 0..1
    const int l31  = lane & 31;
    const int hl   = lane >> 5;  // 0..1
    const int q0   = blockIdx.x * 64;
    const int bh   = blockIdx.y;
    const int b    = bh >> 4;

    const __bf16* Qb  = Q + (size_t)bh * SS * DHD;
    const __bf16* Kb  = K + (size_t)bh * SS * DHD;
    const __bf16* VTb = VT + (size_t)bh * DHD * SS;
    const int*    mb  = mask + (size_t)b * SS * SS;
    const int*    fl  = flags + ((size_t)b * 32 + blockIdx.x) * 32;

    // Q A-frags: Q[q0+w*32+l31][ks*16 + hl*8 + j], pre-scaled 0.125*log2(e)
    bf16_8 qa[4];
#pragma unroll
    for (int ks = 0; ks < 4; ++ks) {
        bf16_8 t = *(const bf16_8*)&Qb[(size_t)(q0 + w * 32 + l31) * DHD +
                                       ks * 16 + hl * 8];
#pragma unroll
        for (int e = 0; e < 8; ++e)
            qa[ks][e] = (__bf16)((float)t[e] * 0.18033688011112042f);
    }

    f32_16 of0 = {}, of1 = {};
    float li[16];
#pragma unroll
    for (int r = 0; r < 16; ++r) li[r] = 0.f;

    // staging: 1024 x 16B chunks over 128 lanes -> 8 per lane (4 K, 4 VT)
    const int rK = tid >> 3;   // 0..15
    const int cp = tid & 7;
    uint4 pre[8];
#pragma unroll
    for (int i = 0; i < 4; ++i) {
        pre[i]     = *(const uint4*)&Kb[(size_t)(rK + i * 16) * DHD + cp * 8];
        pre[4 + i] = *(const uint4*)&VTb[(size_t)(rK + i * 16) * SS + cp * 8];
    }

    for (int k0 = 0; k0 < SS; k0 += 64) {
#pragma unroll
        for (int i = 0; i < 4; ++i) {
            *(uint4*)&ldsK[(rK + i * 16) * 72 + cp * 8]  = pre[i];
            *(uint4*)&ldsVT[(rK + i * 16) * 72 + cp * 8] = pre[4 + i];
        }
        if (k0 + 64 < SS) {  // prefetch next tile (overlaps compute below)
            const int kn = k0 + 64;
#pragma unroll
            for (int i = 0; i < 4; ++i) {
                pre[i]     = *(const uint4*)&Kb[(size_t)(kn + rK + i * 16) * DHD + cp * 8];
                pre[4 + i] = *(const uint4*)&VTb[(size_t)(rK + i * 16) * SS + kn + cp * 8];
            }
        }
        __syncthreads();  // A: staged tile visible

        const bool msk = (fl[k0 >> 6] != 0);

        // S = (Q') K^T ; p = exp2(s); scatter P into own wave's ldsP rows
#pragma unroll
        for (int jt = 0; jt < 2; ++jt) {
            f32_16 s = {};
#pragma unroll
            for (int ks = 0; ks < 4; ++ks) {
                bf16_8 kb = *(const bf16_8*)&ldsK[(jt * 32 + l31) * 72 +
                                                  ks * 16 + hl * 8];
                s = __builtin_amdgcn_mfma_f32_32x32x16_bf16(qa[ks], kb, s, 0, 0, 0);
            }
            if (msk) {
#pragma unroll
                for (int r = 0; r < 16; ++r) {
                    const int row = (r & 3) + 8 * (r >> 2) + 4 * hl;
                    const int qg  = q0 + w * 32 + row;
                    const int kg  = k0 + jt * 32 + l31;
                    if (mb[(size_t)qg * SS + kg] == 0) s[r] = -1e9f;
                }
            }
#pragma unroll
            for (int r = 0; r < 16; ++r) {
                const float p = exp2f(s[r]);
                li[r] += p;
                const int row = (r & 3) + 8 * (r >> 2) + 4 * hl;
                ldsP[(w * 32 + row) * 72 + jt * 32 + l31] = (__bf16)p;
            }
        }
        __syncthreads();  // M: P scatter visible; all ldsK reads complete

        // O += P V
#pragma unroll
        for (int ks2 = 0; ks2 < 4; ++ks2) {
            bf16_8 pa  = *(const bf16_8*)&ldsP[(w * 32 + l31) * 72 +
                                               ks2 * 16 + hl * 8];
            bf16_8 vb0 = *(const bf16_8*)&ldsVT[(l31) * 72 + ks2 * 16 + hl * 8];
            bf16_8 vb1 = *(const bf16_8*)&ldsVT[(32 + l31) * 72 + ks2 * 16 + hl * 8];
            of0 = __builtin_amdgcn_mfma_f32_32x32x16_bf16(pa, vb0, of0, 0, 0, 0);
            of1 = __builtin_amdgcn_mfma_f32_32x32x16_bf16(pa, vb1, of1, 0, 0, 0);
        }
        __syncthreads();  // B: VT/P reads done before next staging overwrites
    }

    // reduce li across the 32 col-lanes of each row, normalize, store O
    const int hcol = (bh & 15) * 64;
#pragma unroll
    for (int r = 0; r < 16; ++r) {
        float ls = li[r];
        ls += __shfl_xor(ls, 1);
        ls += __shfl_xor(ls, 2);
        ls += __shfl_xor(ls, 4);
        ls += __shfl_xor(ls, 8);
        ls += __shfl_xor(ls, 16);
        const float inv = 1.0f / fmaxf(ls, 1e-37f);
        const int row = (r & 3) + 8 * (r >> 2) + 4 * hl;
        const int qg  = q0 + w * 32 + row;
        O[((size_t)b * SS + qg) * DD + hcol + l31]      = (__bf16)(of0[r] * inv);
        O[((size_t)b * SS + qg) * DD + hcol + 32 + l31] = (__bf16)(of1[r] * inv);
    }
}

// ---------------------------------------------------------------------------

extern "C" void kernel_launch(void* const* d_in, const int* in_sizes, int n_in,
                              void* d_out, int out_size, void* d_ws, size_t ws_size,
                              hipStream_t stream) {
    const float* xq   = (const float*)d_in[0];
    const float* xkv  = (const float*)d_in[1];
    const int*   mask = (const int*)d_in[2];
    const float* Wq   = (const float*)d_in[3];
    const float* bq   = (const float*)d_in[4];
    const float* Wk   = (const float*)d_in[5];
    const float* bk   = (const float*)d_in[6];
    const float* Wv   = (const float*)d_in[7];
    const float* bv   = (const float*)d_in[8];
    const float* Wo   = (const float*)d_in[9];
    const float* bo   = (const float*)d_in[10];

    __bf16* ws = (__bf16*)d_ws;
    const size_t big = (size_t)BB * SS * DD;  // 4,194,304
    const size_t wsz = (size_t)DD * DD;       // 1,048,576
    __bf16* Qw   = ws;
    __bf16* Kw   = Qw + big;
    __bf16* VTw  = Kw + big;
    __bf16* Aw   = VTw + big;
    __bf16* Xqb  = Aw + big;
    __bf16* Xkvb = Xqb + big;
    __bf16* Wqb  = Xkvb + big;
    __bf16* Wkb  = Wqb + wsz;
    __bf16* Wvb  = Wkb + wsz;
    __bf16* Wob  = Wvb + wsz;
    int* flags   = (int*)(Wob + wsz);  // 2048 ints

    conv_all<<<dim3(4096, 6), dim3(256), 0, stream>>>(xq, xkv, Wq, Wk, Wv, Wo,
                                                      Xqb, Xkvb, Wqb, Wkb, Wvb, Wob);
    mask_flags_k<<<dim3(2048), dim3(256), 0, stream>>>(mask, flags);
    gemm_qkv<<<dim3(32, 8, 3), dim3(256), 0, stream>>>(Xqb, Xkvb, Wqb, bq, Wkb, bk,
                                                       Wvb, bv, Qw, Kw, VTw);
    flash_attn<<<dim3(SS / 64, BB * NH), dim3(128), 0, stream>>>(Qw, Kw, VTw, mask,
                                                                 flags, Aw);
    gemm_final<<<dim3(64, 16), dim3(256), 0, stream>>>(Aw, Wob, bo, (float*)d_out);
}

// Round 8
// 268.093 us; speedup vs baseline: 1.5097x; 1.3356x over previous
//
#include <hip/hip_runtime.h>
#include <hip/hip_bf16.h>

typedef __bf16 bf16_8  __attribute__((ext_vector_type(8)));
typedef __bf16 bf16_4  __attribute__((ext_vector_type(4)));
typedef float  f32_4   __attribute__((ext_vector_type(4)));

#define NH 16
#define DHD 64
#define BB 2
#define SS 2048
#define DD 1024

// async global->LDS, 16B per lane; LDS dest must be wave-uniform base + lane*16
__device__ __forceinline__ void gload16(const __bf16* g, __bf16* l) {
    __builtin_amdgcn_global_load_lds(
        (const __attribute__((address_space(1))) void*)g,
        (__attribute__((address_space(3))) void*)l, 16, 0, 0);
}

// ---------------------------------------------------------------------------
// f32 -> bf16 conversions, one kernel (y selects tensor)
// ---------------------------------------------------------------------------
__global__ __launch_bounds__(256) void conv_all(
    const float* __restrict__ s0, const float* __restrict__ s1,
    const float* __restrict__ s2, const float* __restrict__ s3,
    const float* __restrict__ s4, const float* __restrict__ s5,
    __bf16* __restrict__ d0, __bf16* __restrict__ d1, __bf16* __restrict__ d2,
    __bf16* __restrict__ d3, __bf16* __restrict__ d4, __bf16* __restrict__ d5) {
    const int y = blockIdx.y;
    if (y >= 2 && blockIdx.x >= 1024) return;
    const float* s = (y == 0) ? s0 : (y == 1) ? s1 : (y == 2) ? s2
                   : (y == 3) ? s3 : (y == 4) ? s4 : s5;
    __bf16* d      = (y == 0) ? d0 : (y == 1) ? d1 : (y == 2) ? d2
                   : (y == 3) ? d3 : (y == 4) ? d4 : d5;
    const int i = (blockIdx.x * 256 + threadIdx.x) * 4;
    f32_4 v = *(const f32_4*)&s[i];
    bf16_4 o; o[0] = (__bf16)v[0]; o[1] = (__bf16)v[1];
    o[2] = (__bf16)v[2]; o[3] = (__bf16)v[3];
    *(bf16_4*)&d[i] = o;
}

// ---------------------------------------------------------------------------
// mask summary: flag[b][qt64][kt64] = 1 if any zero in that 64x64 tile
// ---------------------------------------------------------------------------
__global__ __launch_bounds__(256) void mask_flags_k(const int* __restrict__ mask,
                                                    int* __restrict__ flags) {
    const int id = blockIdx.x;  // b*1024 + qt*32 + kt
    const int b = id >> 10, qt = (id >> 5) & 31, kt = id & 31;
    const int t = threadIdx.x;
    const int row = t >> 2, seg = t & 3;
    const int* p = mask + ((size_t)b * SS + qt * 64 + row) * SS + kt * 64 + seg * 16;
    int any0 = 0;
#pragma unroll
    for (int i = 0; i < 4; ++i) {
        int4 v = *(const int4*)&p[i * 4];
        any0 |= (v.x == 0) | (v.y == 0) | (v.z == 0) | (v.w == 0);
    }
    unsigned long long bal = __ballot(any0);
    __shared__ int sf[4];
    if ((t & 63) == 0) sf[t >> 6] = (bal != 0ULL);
    __syncthreads();
    if (t == 0) flags[id] = sf[0] | sf[1] | sf[2] | sf[3];
}

// ---------------------------------------------------------------------------
// 128x128 GEMM (m97 recipe), C = A * W^T + bias
// LAYOUT 0: (b,h,s,dh) bf16;  LAYOUT 2: V^T (b,h,dh,s) bf16 packed stores.
// ---------------------------------------------------------------------------
template <int LAYOUT>
__device__ __forceinline__ void gemm_body(const __bf16* __restrict__ A,
                                          const __bf16* __restrict__ W,
                                          const float* __restrict__ bias,
                                          __bf16* __restrict__ out,
                                          __bf16* ldsA, __bf16* ldsB) {
    const int tid  = threadIdx.x;
    const int lane = tid & 63;
    const int w    = tid >> 6;
    const int quad = lane >> 4;
    const int l15  = lane & 15;
    const int wm   = (w >> 1) * 64;
    const int wn   = (w & 1) * 64;
    const int m0   = blockIdx.x * 128;
    const int n0   = blockIdx.y * 128;

    f32_4 acc[4][4] = {};

    for (int kt = 0; kt < 1024; kt += 32) {
#pragma unroll
        for (int cc = 0; cc < 2; ++cc) {
            const int c   = tid + cc * 256;
            const int row = c >> 2;
            const int cp  = c & 3;
            gload16(&A[(size_t)(m0 + row) * 1024 + kt + cp * 8], &ldsA[c * 8]);
            gload16(&W[(size_t)(n0 + row) * 1024 + kt + cp * 8], &ldsB[c * 8]);
        }
        __syncthreads();

        bf16_8 af[4], bfr[4];
#pragma unroll
        for (int i = 0; i < 4; ++i)
            af[i] = *(const bf16_8*)&ldsA[(wm + i * 16 + l15) * 32 + quad * 8];
#pragma unroll
        for (int j = 0; j < 4; ++j)
            bfr[j] = *(const bf16_8*)&ldsB[(wn + j * 16 + l15) * 32 + quad * 8];
#pragma unroll
        for (int i = 0; i < 4; ++i)
#pragma unroll
            for (int j = 0; j < 4; ++j)
                acc[i][j] = __builtin_amdgcn_mfma_f32_16x16x32_bf16(
                    af[i], bfr[j], acc[i][j], 0, 0, 0);
        __syncthreads();
    }

#pragma unroll
    for (int i = 0; i < 4; ++i) {
#pragma unroll
        for (int j = 0; j < 4; ++j) {
            const int col = n0 + wn + j * 16 + l15;
            const float bv = bias[col];
            if (LAYOUT == 2) {
                const int row0 = m0 + wm + i * 16 + quad * 4;
                bf16_4 pk;
#pragma unroll
                for (int r = 0; r < 4; ++r) pk[r] = (__bf16)(acc[i][j][r] + bv);
                const int bb = row0 >> 11, s0 = row0 & 2047;
                const int h = col >> 6, dh = col & 63;
                *(bf16_4*)&out[(((size_t)bb * NH + h) * DHD + dh) * SS + s0] = pk;
            } else {
#pragma unroll
                for (int r = 0; r < 4; ++r) {
                    const int row = m0 + wm + i * 16 + quad * 4 + r;
                    out[(((size_t)(row >> 11) * NH + (col >> 6)) * SS +
                         (row & 2047)) * DHD + (col & 63)] =
                        (__bf16)(acc[i][j][r] + bv);
                }
            }
        }
    }
}

__global__ __launch_bounds__(256) void gemm_qkv(
    const __bf16* __restrict__ Xq, const __bf16* __restrict__ Xkv,
    const __bf16* __restrict__ Wq, const float* __restrict__ bq,
    const __bf16* __restrict__ Wk, const float* __restrict__ bk,
    const __bf16* __restrict__ Wv, const float* __restrict__ bv,
    __bf16* __restrict__ Qo, __bf16* __restrict__ Ko, __bf16* __restrict__ VTo) {
    __shared__ __align__(16) __bf16 ldsA[128 * 32];
    __shared__ __align__(16) __bf16 ldsB[128 * 32];
    const int z = blockIdx.z;
    const __bf16* A    = (z == 0) ? Xq : Xkv;
    const __bf16* W    = (z == 0) ? Wq : (z == 1 ? Wk : Wv);
    const float* bias  = (z == 0) ? bq : (z == 1 ? bk : bv);
    if (z == 2)
        gemm_body<2>(A, W, bias, VTo, ldsA, ldsB);
    else
        gemm_body<0>(A, W, bias, (z == 0) ? Qo : Ko, ldsA, ldsB);
}

// ---------------------------------------------------------------------------
// Final projection: 64x64 tile, BK=32, 1024 blocks (4/CU). out = f32 row-major.
// ---------------------------------------------------------------------------
__global__ __launch_bounds__(256) void gemm_final(
    const __bf16* __restrict__ A, const __bf16* __restrict__ W,
    const float* __restrict__ bias, float* __restrict__ out) {
    __shared__ __align__(16) __bf16 ldsA[64 * 32];
    __shared__ __align__(16) __bf16 ldsB[64 * 32];
    const int tid  = threadIdx.x;
    const int lane = tid & 63;
    const int w    = tid >> 6;
    const int quad = lane >> 4;
    const int l15  = lane & 15;
    const int wm   = (w >> 1) * 32;
    const int wn   = (w & 1) * 32;
    const int m0   = blockIdx.x * 64;
    const int n0   = blockIdx.y * 64;

    const int isB = w >> 1;
    const __bf16* src = isB ? W : A;
    const int     bN  = isB ? n0 : m0;
    __bf16*       dst = isB ? ldsB : ldsA;
    const int     w2  = w & 1;

    f32_4 acc[2][2] = {};

    for (int kt = 0; kt < 1024; kt += 32) {
#pragma unroll
        for (int cc = 0; cc < 2; ++cc) {
            const int c   = w2 * 128 + cc * 64 + lane;
            const int row = c >> 2;
            const int cp  = c & 3;
            gload16(&src[(size_t)(bN + row) * 1024 + kt + cp * 8], &dst[c * 8]);
        }
        __syncthreads();

        bf16_8 af[2], bfr[2];
#pragma unroll
        for (int i = 0; i < 2; ++i)
            af[i] = *(const bf16_8*)&ldsA[(wm + i * 16 + l15) * 32 + quad * 8];
#pragma unroll
        for (int j = 0; j < 2; ++j)
            bfr[j] = *(const bf16_8*)&ldsB[(wn + j * 16 + l15) * 32 + quad * 8];
#pragma unroll
        for (int i = 0; i < 2; ++i)
#pragma unroll
            for (int j = 0; j < 2; ++j)
                acc[i][j] = __builtin_amdgcn_mfma_f32_16x16x32_bf16(
                    af[i], bfr[j], acc[i][j], 0, 0, 0);
        __syncthreads();
    }

#pragma unroll
    for (int i = 0; i < 2; ++i)
#pragma unroll
        for (int j = 0; j < 2; ++j) {
            const int col = n0 + wn + j * 16 + l15;
            const float bv = bias[col];
#pragma unroll
            for (int r = 0; r < 4; ++r) {
                const int row = m0 + wm + i * 16 + quad * 4 + r;
                out[(size_t)row * 1024 + col] = acc[i][j][r] + bv;
            }
        }
}

// ---------------------------------------------------------------------------
// Flash attention v5: 16x16x32 MFMA only (f32_4 tuples -> no tuple-alloc
// spill; v1-proven), but 32 q-rows per wave (mt=2) to double MFMA per LDS
// read. Block = 256 threads (4 waves), q-tile 128, k-tiles of 64.
// 3 barriers/tile (round-6 lesson: no same-wave LDS write->read assumptions).
// LDS: ldsK 64x72 + ldsVT 64x72 + ldsP 128x72 = 36 KB -> 2 blocks/CU (grid
// 512 = 2/CU anyway). launch_bounds(256,2) keeps VGPR cap at 256 so the
// ~140-reg live set doesn't spill against an LDS-implied occupancy cap.
// No-max softmax in exp2 domain (Q pre-scaled by 0.125*log2e).
// ---------------------------------------------------------------------------
__global__ __launch_bounds__(256, 2) void flash_attn(
    const __bf16* __restrict__ Q, const __bf16* __restrict__ K,
    const __bf16* __restrict__ VT, const int* __restrict__ mask,
    const int* __restrict__ flags, __bf16* __restrict__ O) {
    __shared__ __align__(16) __bf16 ldsK[64 * 72];
    __shared__ __align__(16) __bf16 ldsVT[64 * 72];
    __shared__ __align__(16) __bf16 ldsP[128 * 72];

    const int tid  = threadIdx.x;
    const int lane = tid & 63;
    const int w    = tid >> 6;   // 0..3
    const int quad = lane >> 4;
    const int l15  = lane & 15;
    const int q0   = blockIdx.x * 128;
    const int bh   = blockIdx.y;
    const int b    = bh >> 4;

    const __bf16* Qb  = Q + (size_t)bh * SS * DHD;
    const __bf16* Kb  = K + (size_t)bh * SS * DHD;
    const __bf16* VTb = VT + (size_t)bh * DHD * SS;
    const int*    mb  = mask + (size_t)b * SS * SS;
    const int*    flb = flags + (size_t)b * 1024 + blockIdx.x * 64;  // two 64-row subtiles

    // Q A-frags (m=l15, k=quad*8+e), pre-scaled by 0.125*log2(e)
    bf16_8 qa[2][2];
#pragma unroll
    for (int mt = 0; mt < 2; ++mt)
#pragma unroll
        for (int ks = 0; ks < 2; ++ks) {
            bf16_8 t = *(const bf16_8*)&Qb[(size_t)(q0 + w * 32 + mt * 16 + l15) * DHD +
                                           ks * 32 + quad * 8];
#pragma unroll
            for (int e = 0; e < 8; ++e)
                qa[mt][ks][e] = (__bf16)((float)t[e] * 0.18033688011112042f);
        }

    f32_4 of[2][4] = {};
    float li[2][4] = {};

    // staging: 512 K-chunks + 512 VT-chunks of 16B over 256 lanes (2+2 each)
    const int r0 = tid >> 3;        // 0..31
    const int r1 = r0 + 32;         // 32..63
    const int cp = tid & 7;
    uint4 kr0 = *(const uint4*)&Kb[(size_t)r0 * DHD + cp * 8];
    uint4 kr1 = *(const uint4*)&Kb[(size_t)r1 * DHD + cp * 8];
    uint4 vr0 = *(const uint4*)&VTb[(size_t)r0 * SS + cp * 8];
    uint4 vr1 = *(const uint4*)&VTb[(size_t)r1 * SS + cp * 8];

    for (int k0 = 0; k0 < SS; k0 += 64) {
        *(uint4*)&ldsK[r0 * 72 + cp * 8]  = kr0;
        *(uint4*)&ldsK[r1 * 72 + cp * 8]  = kr1;
        *(uint4*)&ldsVT[r0 * 72 + cp * 8] = vr0;
        *(uint4*)&ldsVT[r1 * 72 + cp * 8] = vr1;
        if (k0 + 64 < SS) {  // prefetch next tile (overlaps compute below)
            const int kn = k0 + 64;
            kr0 = *(const uint4*)&Kb[(size_t)(kn + r0) * DHD + cp * 8];
            kr1 = *(const uint4*)&Kb[(size_t)(kn + r1) * DHD + cp * 8];
            vr0 = *(const uint4*)&VTb[(size_t)r0 * SS + kn + cp * 8];
            vr1 = *(const uint4*)&VTb[(size_t)r1 * SS + kn + cp * 8];
        }
        __syncthreads();  // A: staged tile visible

        const bool msk = ((flb[k0 >> 6] | flb[32 + (k0 >> 6)]) != 0);

        // S = (Q') K^T : 2 mt x 4 j tiles of 16x16, k = dh 64 in 2 slices
        f32_4 sa[2][4] = {};
#pragma unroll
        for (int ks = 0; ks < 2; ++ks) {
            bf16_8 kb[4];
#pragma unroll
            for (int j = 0; j < 4; ++j)
                kb[j] = *(const bf16_8*)&ldsK[(j * 16 + l15) * 72 + ks * 32 + quad * 8];
#pragma unroll
            for (int mt = 0; mt < 2; ++mt)
#pragma unroll
                for (int j = 0; j < 4; ++j)
                    sa[mt][j] = __builtin_amdgcn_mfma_f32_16x16x32_bf16(
                        qa[mt][ks], kb[j], sa[mt][j], 0, 0, 0);
        }

        if (msk) {  // uniform slow path
#pragma unroll
            for (int mt = 0; mt < 2; ++mt)
#pragma unroll
                for (int j = 0; j < 4; ++j)
#pragma unroll
                    for (int r = 0; r < 4; ++r) {
                        const int qg = q0 + w * 32 + mt * 16 + quad * 4 + r;
                        const int kg = k0 + j * 16 + l15;
                        if (mb[(size_t)qg * SS + kg] == 0) sa[mt][j][r] = -1e9f;
                    }
        }

        // p = exp2(s); per-lane partial sums; P scatter (C-layout) to LDS
#pragma unroll
        for (int mt = 0; mt < 2; ++mt)
#pragma unroll
            for (int j = 0; j < 4; ++j)
#pragma unroll
                for (int r = 0; r < 4; ++r) {
                    const float p = exp2f(sa[mt][j][r]);
                    li[mt][r] += p;
                    ldsP[(w * 32 + mt * 16 + quad * 4 + r) * 72 + j * 16 + l15] =
                        (__bf16)p;
                }
        __syncthreads();  // M: P visible; all ldsK reads complete

        // O += P V
#pragma unroll
        for (int ks2 = 0; ks2 < 2; ++ks2) {
            bf16_8 pa[2], vb[4];
#pragma unroll
            for (int mt = 0; mt < 2; ++mt)
                pa[mt] = *(const bf16_8*)&ldsP[(w * 32 + mt * 16 + l15) * 72 +
                                               ks2 * 32 + quad * 8];
#pragma unroll
            for (int jo = 0; jo < 4; ++jo)
                vb[jo] = *(const bf16_8*)&ldsVT[(jo * 16 + l15) * 72 +
                                                ks2 * 32 + quad * 8];
#pragma unroll
            for (int mt = 0; mt < 2; ++mt)
#pragma unroll
                for (int jo = 0; jo < 4; ++jo)
                    of[mt][jo] = __builtin_amdgcn_mfma_f32_16x16x32_bf16(
                        pa[mt], vb[jo], of[mt][jo], 0, 0, 0);
        }
        __syncthreads();  // B: VT/P reads done before next staging overwrites
    }

    // reduce li across the 16 lanes of each row, normalize, store O
    const int hcol = (bh & 15) * 64;
#pragma unroll
    for (int mt = 0; mt < 2; ++mt)
#pragma unroll
        for (int r = 0; r < 4; ++r) {
            float ls = li[mt][r];
            ls += __shfl_xor(ls, 1);
            ls += __shfl_xor(ls, 2);
            ls += __shfl_xor(ls, 4);
            ls += __shfl_xor(ls, 8);
            const float inv = 1.0f / fmaxf(ls, 1e-37f);
            const int qg = q0 + w * 32 + mt * 16 + quad * 4 + r;
#pragma unroll
            for (int jo = 0; jo < 4; ++jo)
                O[((size_t)b * SS + qg) * DD + hcol + jo * 16 + l15] =
                    (__bf16)(of[mt][jo][r] * inv);
        }
}

// ---------------------------------------------------------------------------

extern "C" void kernel_launch(void* const* d_in, const int* in_sizes, int n_in,
                              void* d_out, int out_size, void* d_ws, size_t ws_size,
                              hipStream_t stream) {
    const float* xq   = (const float*)d_in[0];
    const float* xkv  = (const float*)d_in[1];
    const int*   mask = (const int*)d_in[2];
    const float* Wq   = (const float*)d_in[3];
    const float* bq   = (const float*)d_in[4];
    const float* Wk   = (const float*)d_in[5];
    const float* bk   = (const float*)d_in[6];
    const float* Wv   = (const float*)d_in[7];
    const float* bv   = (const float*)d_in[8];
    const float* Wo   = (const float*)d_in[9];
    const float* bo   = (const float*)d_in[10];

    __bf16* ws = (__bf16*)d_ws;
    const size_t big = (size_t)BB * SS * DD;  // 4,194,304
    const size_t wsz = (size_t)DD * DD;       // 1,048,576
    __bf16* Qw   = ws;
    __bf16* Kw   = Qw + big;
    __bf16* VTw  = Kw + big;
    __bf16* Aw   = VTw + big;
    __bf16* Xqb  = Aw + big;
    __bf16* Xkvb = Xqb + big;
    __bf16* Wqb  = Xkvb + big;
    __bf16* Wkb  = Wqb + wsz;
    __bf16* Wvb  = Wkb + wsz;
    __bf16* Wob  = Wvb + wsz;
    int* flags   = (int*)(Wob + wsz);  // 2048 ints

    conv_all<<<dim3(4096, 6), dim3(256), 0, stream>>>(xq, xkv, Wq, Wk, Wv, Wo,
                                                      Xqb, Xkvb, Wqb, Wkb, Wvb, Wob);
    mask_flags_k<<<dim3(2048), dim3(256), 0, stream>>>(mask, flags);
    gemm_qkv<<<dim3(32, 8, 3), dim3(256), 0, stream>>>(Xqb, Xkvb, Wqb, bq, Wkb, bk,
                                                       Wvb, bv, Qw, Kw, VTw);
    flash_attn<<<dim3(SS / 128, BB * NH), dim3(256), 0, stream>>>(Qw, Kw, VTw, mask,
                                                                  flags, Aw);
    gemm_final<<<dim3(64, 16), dim3(256), 0, stream>>>(Aw, Wob, bo, (float*)d_out);
}